// Round 9
// baseline (54.307 us; speedup 1.0000x reference)
//
#include <hip/hip_runtime.h>
#include <hip/hip_bf16.h>

#define NB   16
#define CINC 64
#define COUTC 64
#define NV   25
#define TLEN 512
#define KK   3
#define TKK  3

typedef short short8 __attribute__((ext_vector_type(8)));
typedef float f32x4  __attribute__((ext_vector_type(4)));
typedef float f32x16 __attribute__((ext_vector_type(16)));

#define XT_ROWS 514        // padded: row 0 = t=-1 (zero), rows 1..512 = t, row 513 = t=512 (zero)
#define XS_BYTES 16640     // 130 rows * 128 B per slab buffer
#define NWT3BLK (NV * 9)   // 225 weight-prep blocks

__device__ __forceinline__ unsigned pack_bf16(float lo, float hi) {
  __hip_bfloat16 l = __float2bfloat16(lo);
  __hip_bfloat16 h = __float2bfloat16(hi);
  unsigned short ul = *reinterpret_cast<unsigned short*>(&l);
  unsigned short uh = *reinterpret_cast<unsigned short*>(&h);
  return (unsigned)ul | ((unsigned)uh << 16);
}

// ================= fused prep: Wt3 (blocks 0..224) + padded xT (rest) ========
// Wt3[blk=(v*3+k)*3+kt][oslab][ks][lane][e] bf16, mask folded in.
//   o = oslab*32 + (lane&31);  c = ks*16 + 8*(lane>>5) + e
// xT[n][v][rp][c] bf16, rp = t+1, rows 0 and 513 zeroed.
__global__ __launch_bounds__(256) void prep_all(
    const float* __restrict__ x, const float* __restrict__ W,
    const unsigned char* __restrict__ mask_raw,
    __hip_bfloat16* __restrict__ Wt3, __hip_bfloat16* __restrict__ xT) {
  __shared__ float ts[64][65];
  int bid = blockIdx.x;
  if (bid < NWT3BLK) {
    int blk = bid;                 // v*9 + k*3 + kt
    int v = blk / 9, kkt = blk % 9, k = kkt / 3, kt = kkt % 3;
    const int* mi = (const int*)mask_raw;
    int ok = 1;
    for (int i = 0; i < 18; ++i) {
      int m = mi[i];
      if (m != 0 && m != 1) ok = 0;
    }
    int m = ok ? mi[v * KK + k] : (int)(mask_raw[v * KK + k] != 0);
    const float* Wv = W + (size_t)v * COUTC * CINC * 9;
    __hip_bfloat16* dst = Wt3 + (size_t)blk * 4096;
    for (int i = threadIdx.x; i < 4096; i += 256) {
      int e     = i & 7;
      int lane  = (i >> 3) & 63;
      int ks    = (i >> 9) & 3;
      int oslab = i >> 11;
      int o = oslab * 32 + (lane & 31);
      int c = ks * 16 + 8 * (lane >> 5) + e;
      float val = m ? Wv[(o * CINC + c) * 9 + k * 3 + kt] : 0.f;
      dst[i] = __float2bfloat16(val);
    }
    return;
  }
  bid -= NWT3BLK;
  const int tb = (bid & 7) * 64;
  const int vn = bid >> 3;
  const int v  = vn % NV;
  const int n  = vn / NV;
  const int tid = threadIdx.x;
  // load: float4 over t (coalesced), transpose via LDS (stride 65: <=2-way)
  for (int i = tid; i < 1024; i += 256) {
    int c = i >> 4, tq = (i & 15) * 4;
    float4 val = *(const float4*)(x + (((size_t)n * CINC + c) * NV + v) * TLEN + tb + tq);
    ts[c][tq + 0] = val.x;
    ts[c][tq + 1] = val.y;
    ts[c][tq + 2] = val.z;
    ts[c][tq + 3] = val.w;
  }
  __syncthreads();
  // emit packed bf16 pairs; 256 B contiguous per wave-instr
  unsigned* base = (unsigned*)(xT + ((size_t)(n * NV + v) * XT_ROWS) * CINC);
  for (int i = tid; i < 2048; i += 256) {
    int c2 = i & 31, t = i >> 5;
    base[(tb + 1 + t) * 32 + c2] = pack_bf16(ts[2 * c2][t], ts[2 * c2 + 1][t]);
  }
  // zero halo rows
  if (tb == 0 && tid < 32) base[tid] = 0u;
  if (tb == TLEN - 64 && tid < 32) base[513 * 32 + tid] = 0u;
}

__device__ __forceinline__ const char* slab_base(const __hip_bfloat16* xT,
                                                 int n, int vk, int tb) {
  return (const char*)xT + ((size_t)(n * NV + vk) * XT_ROWS + tb) * 128;
}

// Main: block = 64 o x 128 t for (tchunk, n, v). 4 waves: wave = (oslab, t-half).
// R8 lesson: the 36-frag A-prefetch (144 VGPR, launch_bounds 2) capped static
// occupancy at 8 waves/CU, and with ~5 resident waves ALL pipes serialized
// (sum of per-CU pipe times ~= measured 37us). This round trades the single
// vmcnt window back for TLP: per-k A-frags (48 VGPR, 3 small windows/wave,
// '#pragma unroll 1' stops re-hoisting), ~130 VGPR + 50KB LDS -> 3 blocks/CU
// = 12 waves/CU. Sibling waves/blocks hide each other's windows and drains.
__global__ __launch_bounds__(256, 3) void lcn_mfma32(
    const __hip_bfloat16* __restrict__ xT,
    const __hip_bfloat16* __restrict__ Wt3,
    const float* __restrict__ bias,
    const int* __restrict__ idx,
    float* __restrict__ out) {
  __shared__ char xs[KK][XS_BYTES];   // 3 slabs, 49,920 B

  const int tb   = blockIdx.x * 128;
  const int n    = blockIdx.y;
  const int v    = blockIdx.z;
  const int tid  = threadIdx.x;
  const int lane = tid & 63;
  const int wave = tid >> 6;
  const int os   = wave & 1;     // this wave's o-slab
  const int th   = wave >> 1;    // this wave's 64-t half
  const int hi   = lane >> 5;
  const int l31  = lane & 31;

  // issue async staging of all 3 neighbor slabs (no VGPR round-trip)
  {
    const char* g0 = slab_base(xT, n, idx[v * KK + 0], tb);
    const char* g1 = slab_base(xT, n, idx[v * KK + 1], tb);
    const char* g2 = slab_base(xT, n, idx[v * KK + 2], tb);
    for (int j = wave; j < 3 * 17; j += 4) {
      int slab = j / 17, c = j % 17;
      const char* gb = slab == 0 ? g0 : (slab == 1 ? g1 : g2);
      int L = c * 1024 + lane * 16;
      if (L < XS_BYTES) {
        int g = L ^ (((L >> 7) & 7) << 4);   // XOR bits 4-6 by row bits 7-9
        __builtin_amdgcn_global_load_lds(
            (const __attribute__((address_space(1))) void*)(gb + g),
            (__attribute__((address_space(3))) void*)(&xs[slab][c * 1024]),
            16, 0, 0);
      }
    }
  }
  __syncthreads();   // the only barrier in the kernel

  f32x16 acc0 = {}, acc1 = {};   // t-subtile 0 / 1 of this wave's 64-t half

#pragma unroll 1
  for (int k = 0; k < KK; ++k) {
    const char* cb = xs[k];
    // A-frags for this k only (48 VGPR): one o-slab, all kt/ks
    short8 a[TKK][4];
    {
      const short8* wb = (const short8*)Wt3 +
                         ((size_t)((v * KK + k) * TKK) * 2 + os) * 256 + lane;
#pragma unroll
      for (int kt = 0; kt < TKK; ++kt)
#pragma unroll
        for (int ks = 0; ks < 4; ++ks)
          a[kt][ks] = wb[kt * 512 + (ks << 6)];
    }
#pragma unroll
    for (int kt = 0; kt < TKK; ++kt) {
      {
        const int r  = th * 64 + l31 + kt;
        const int sw = (r & 7) << 4;
        const int co = hi * 16;
        const char* bp = cb + r * 128;
#pragma unroll
        for (int ks = 0; ks < 4; ++ks) {
          short8 bfr = *(const short8*)(bp + ((co + 32 * ks) ^ sw));
          acc0 = __builtin_amdgcn_mfma_f32_32x32x16_bf16(a[kt][ks], bfr, acc0, 0, 0, 0);
        }
      }
      {
        const int r  = th * 64 + 32 + l31 + kt;
        const int sw = (r & 7) << 4;
        const int co = hi * 16;
        const char* bp = cb + r * 128;
#pragma unroll
        for (int ks = 0; ks < 4; ++ks) {
          short8 bfr = *(const short8*)(bp + ((co + 32 * ks) ^ sw));
          acc1 = __builtin_amdgcn_mfma_f32_32x32x16_bf16(a[kt][ks], bfr, acc1, 0, 0, 0);
        }
      }
    }
  }

  // epilogue: D col(t)=lane&31, row(o)=(reg&3)+8*(reg>>2)+4*(lane>>5)
  const float* bv = bias + v * COUTC;
#pragma unroll
  for (int s = 0; s < 2; ++s) {
    const f32x16& acc = s ? acc1 : acc0;
    const int t = tb + th * 64 + s * 32 + l31;
#pragma unroll
    for (int reg = 0; reg < 16; ++reg) {
      int o = os * 32 + 4 * hi + (reg & 3) + 8 * (reg >> 2);
      out[(((size_t)n * COUTC + o) * NV + v) * TLEN + t] = acc[reg] + bv[o];
    }
  }
}

// ================= FALLBACK PATH (round-1 fp32, known-good) =================
__global__ void prep_mask_kernel(const int* __restrict__ mask_raw,
                                 int* __restrict__ mask_out) {
  __shared__ int fmt;
  if (threadIdx.x == 0) {
    int ok = 1;
    for (int i = 0; i < 18; ++i) {
      int m = mask_raw[i];
      if (m != 0 && m != 1) ok = 0;
    }
    fmt = ok;
  }
  __syncthreads();
  int i = threadIdx.x;
  if (i < NV * KK) {
    int m;
    if (fmt) m = mask_raw[i];
    else     m = (((const unsigned char*)mask_raw)[i] != 0) ? 1 : 0;
    mask_out[i] = m;
  }
}

__global__ void prep_wt_kernel(const float* __restrict__ W,
                               float* __restrict__ Wt) {
  int v   = blockIdx.x / 9;
  int kkt = blockIdx.x % 9;
  const float* Wv = W + (size_t)v * COUTC * CINC * 9;
  float* dst = Wt + (size_t)blockIdx.x * (CINC * COUTC);
  for (int i = threadIdx.x; i < CINC * COUTC; i += 256) {
    int c = i >> 6;
    int o = i & 63;
    dst[i] = Wv[(o * CINC + c) * 9 + kkt];
  }
}

__global__ __launch_bounds__(256, 4) void lcn_main(
    const float* __restrict__ x, const float* __restrict__ Wt,
    const float* __restrict__ b, const int* __restrict__ idx,
    const int* __restrict__ maskn, float* __restrict__ out) {
  __shared__ float xsf[CINC][66];
  __shared__ float wsh[CINC][COUTC];
  const int tb  = blockIdx.x * 64;
  const int v   = blockIdx.y;
  const int n   = blockIdx.z;
  const int tid = threadIdx.x;
  const int t0  = tid & 63;
  const int og  = tid >> 6;
  float acc[16];
#pragma unroll
  for (int j = 0; j < 16; ++j) acc[j] = 0.f;
  for (int k = 0; k < KK; ++k) {
    const int vk = idx[v * KK + k];
    const int mk = maskn[v * KK + k];
    __syncthreads();
    for (int i = tid; i < CINC * 66; i += 256) {
      int c  = i / 66;
      int tt = i - c * 66;
      int gt = tb - 1 + tt;
      float val = 0.f;
      if (mk && gt >= 0 && gt < TLEN)
        val = x[(((size_t)n * CINC + c) * NV + vk) * TLEN + gt];
      xsf[c][tt] = val;
    }
    for (int kt = 0; kt < TKK; ++kt) {
      __syncthreads();
      const float4* src =
          (const float4*)(Wt + ((size_t)(v * KK + k) * TKK + kt) * (CINC * COUTC));
      for (int i = tid; i < CINC * COUTC / 4; i += 256)
        ((float4*)wsh)[i] = src[i];
      __syncthreads();
#pragma unroll 4
      for (int c = 0; c < CINC; ++c) {
        float xv = xsf[c][t0 + kt];
        const float4* wrow = (const float4*)&wsh[c][og * 16];
#pragma unroll
        for (int j4 = 0; j4 < 4; ++j4) {
          float4 wv = wrow[j4];
          acc[j4 * 4 + 0] = fmaf(wv.x, xv, acc[j4 * 4 + 0]);
          acc[j4 * 4 + 1] = fmaf(wv.y, xv, acc[j4 * 4 + 1]);
          acc[j4 * 4 + 2] = fmaf(wv.z, xv, acc[j4 * 4 + 2]);
          acc[j4 * 4 + 3] = fmaf(wv.w, xv, acc[j4 * 4 + 3]);
        }
      }
    }
  }
#pragma unroll
  for (int j = 0; j < 16; ++j) {
    int o = og * 16 + j;
    out[(((size_t)n * COUTC + o) * NV + v) * TLEN + tb + t0] =
        acc[j] + b[v * COUTC + o];
  }
}

extern "C" void kernel_launch(void* const* d_in, const int* in_sizes, int n_in,
                              void* d_out, int out_size, void* d_ws, size_t ws_size,
                              hipStream_t stream) {
  const float* x    = (const float*)d_in[0];
  const float* W    = (const float*)d_in[1];
  const float* b    = (const float*)d_in[2];
  const int*   idx  = (const int*)d_in[3];
  const void*  mask = (const void*)d_in[4];
  float* out = (float*)d_out;

  // ws: [0,512) maskn (fallback) | Wt3 1.84MB | xT padded 26.3MB | guard
  const size_t WT3_BYTES = (size_t)NV * 9 * 4096 * sizeof(__hip_bfloat16);
  const size_t XT_BYTES  = (size_t)NB * NV * XT_ROWS * CINC * sizeof(__hip_bfloat16);
  const size_t NEED      = 512 + WT3_BYTES + XT_BYTES + 2048;

  if (ws_size >= NEED) {
    __hip_bfloat16* Wt3 = (__hip_bfloat16*)((char*)d_ws + 512);
    __hip_bfloat16* xT  = (__hip_bfloat16*)((char*)d_ws + 512 + WT3_BYTES);
    hipLaunchKernelGGL(prep_all, dim3(NWT3BLK + 8 * NV * NB), dim3(256), 0,
                       stream, x, W, (const unsigned char*)mask, Wt3, xT);
    hipLaunchKernelGGL(lcn_mfma32, dim3(TLEN / 128, NB, NV), dim3(256), 0,
                       stream, xT, Wt3, b, idx, out);
  } else {
    int*   maskn = (int*)d_ws;
    float* Wt    = (float*)((char*)d_ws + 512);
    hipLaunchKernelGGL(prep_mask_kernel, dim3(1), dim3(128), 0, stream,
                       (const int*)mask, maskn);
    hipLaunchKernelGGL(prep_wt_kernel, dim3(NV * KK * TKK), dim3(256), 0, stream,
                       W, Wt);
    hipLaunchKernelGGL(lcn_main, dim3(TLEN / 64, NV, NB), dim3(256), 0, stream,
                       x, Wt, b, idx, maskn, out);
  }
}

// Round 10
// 46.650 us; speedup vs baseline: 1.1641x; 1.1641x over previous
//
#include <hip/hip_runtime.h>
#include <hip/hip_bf16.h>

#define NB   16
#define CINC 64
#define COUTC 64
#define NV   25
#define TLEN 512
#define KK   3
#define TKK  3

typedef short short8 __attribute__((ext_vector_type(8)));
typedef float f32x4  __attribute__((ext_vector_type(4)));
typedef float f32x16 __attribute__((ext_vector_type(16)));

#define XT_ROWS 514        // padded: row 0 = t=-1 (zero), rows 1..512 = t, row 513 = t=512 (zero)
#define XS_STRIDE 17408    // 17 x 1KB stage ops; used bytes = 130*128 = 16640
#define NWT3BLK (NV * 9)   // 225 weight-prep blocks

__device__ __forceinline__ unsigned pack_bf16(float lo, float hi) {
  __hip_bfloat16 l = __float2bfloat16(lo);
  __hip_bfloat16 h = __float2bfloat16(hi);
  unsigned short ul = *reinterpret_cast<unsigned short*>(&l);
  unsigned short uh = *reinterpret_cast<unsigned short*>(&h);
  return (unsigned)ul | ((unsigned)uh << 16);
}

// ================= fused prep: Wt3 (blocks 0..224) + padded xT (rest) ========
__global__ __launch_bounds__(256) void prep_all(
    const float* __restrict__ x, const float* __restrict__ W,
    const unsigned char* __restrict__ mask_raw,
    __hip_bfloat16* __restrict__ Wt3, __hip_bfloat16* __restrict__ xT) {
  __shared__ float ts[64][65];
  int bid = blockIdx.x;
  if (bid < NWT3BLK) {
    int blk = bid;                 // v*9 + k*3 + kt
    int v = blk / 9, kkt = blk % 9, k = kkt / 3, kt = kkt % 3;
    const int* mi = (const int*)mask_raw;
    int ok = 1;
    for (int i = 0; i < 18; ++i) {
      int m = mi[i];
      if (m != 0 && m != 1) ok = 0;
    }
    int m = ok ? mi[v * KK + k] : (int)(mask_raw[v * KK + k] != 0);
    const float* Wv = W + (size_t)v * COUTC * CINC * 9;
    __hip_bfloat16* dst = Wt3 + (size_t)blk * 4096;
    for (int i = threadIdx.x; i < 4096; i += 256) {
      int e     = i & 7;
      int lane  = (i >> 3) & 63;
      int ks    = (i >> 9) & 3;
      int oslab = i >> 11;
      int o = oslab * 32 + (lane & 31);
      int c = ks * 16 + 8 * (lane >> 5) + e;
      float val = m ? Wv[(o * CINC + c) * 9 + k * 3 + kt] : 0.f;
      dst[i] = __float2bfloat16(val);
    }
    return;
  }
  bid -= NWT3BLK;
  const int tb = (bid & 7) * 64;
  const int vn = bid >> 3;
  const int v  = vn % NV;
  const int n  = vn / NV;
  const int tid = threadIdx.x;
  for (int i = tid; i < 1024; i += 256) {
    int c = i >> 4, tq = (i & 15) * 4;
    float4 val = *(const float4*)(x + (((size_t)n * CINC + c) * NV + v) * TLEN + tb + tq);
    ts[c][tq + 0] = val.x;
    ts[c][tq + 1] = val.y;
    ts[c][tq + 2] = val.z;
    ts[c][tq + 3] = val.w;
  }
  __syncthreads();
  unsigned* base = (unsigned*)(xT + ((size_t)(n * NV + v) * XT_ROWS) * CINC);
  for (int i = tid; i < 2048; i += 256) {
    int c2 = i & 31, t = i >> 5;
    base[(tb + 1 + t) * 32 + c2] = pack_bf16(ts[2 * c2][t], ts[2 * c2 + 1][t]);
  }
  if (tb == 0 && tid < 32) base[tid] = 0u;
  if (tb == TLEN - 64 && tid < 32) base[513 * 32 + tid] = 0u;
}

__device__ __forceinline__ const char* slab_base(const __hip_bfloat16* xT,
                                                 int n, int vk, int tb) {
  return (const char*)xT + ((size_t)(n * NV + vk) * XT_ROWS + tb) * 128;
}

// Main: block = 64 o x 128 t for (tchunk, n, v). 4 waves: wave = (oslab, t-half).
// R9 lesson: every prior round let the compiler drain vmcnt(0) at barriers ->
// all waves park on full L3 staging latency each phase (the documented T3/T4
// stall). This round: COUNTED waits, never 0 in sequence, raw s_barrier.
// Issue order (pinned by sched_barrier): [A0(12)][s0(5)][s1(5)][s2(5)]; A1
// prefetched in k0 region. Static per-wave waits: k0 vmcnt(10), k1 vmcnt(17),
// k2 vmcnt(12). Dummy stage ops keep all waves at exactly 5 ops/slab.
__global__ __launch_bounds__(256, 3) void lcn_mfma32(
    const __hip_bfloat16* __restrict__ xT,
    const __hip_bfloat16* __restrict__ Wt3,
    const float* __restrict__ bias,
    const int* __restrict__ idx,
    float* __restrict__ out) {
  __shared__ char xs[KK][XS_STRIDE];   // 52,224 B
  __shared__ char xs_dummy[1024];      // dummy-op sink (never read)

  const int tb   = blockIdx.x * 128;
  const int n    = blockIdx.y;
  const int v    = blockIdx.z;
  const int tid  = threadIdx.x;
  const int lane = tid & 63;
  const int wave = tid >> 6;
  const int os   = wave & 1;     // this wave's o-slab
  const int th   = wave >> 1;    // this wave's 64-t half
  const int hi   = lane >> 5;
  const int l31  = lane & 31;

#define LOAD_A(DST, KIDX)                                                     \
  {                                                                           \
    const short8* wb = (const short8*)Wt3 +                                   \
        ((size_t)((v * KK + (KIDX)) * TKK) * 2 + os) * 256 + lane;            \
    _Pragma("unroll") for (int kt = 0; kt < TKK; ++kt)                        \
      _Pragma("unroll") for (int ks = 0; ks < 4; ++ks)                        \
        DST[kt * 4 + ks] = wb[kt * 512 + (ks << 6)];                          \
  }

#define COMPUTE_K(CB, A)                                                      \
  _Pragma("unroll") for (int kt = 0; kt < TKK; ++kt) {                        \
    {                                                                         \
      const int r  = th * 64 + l31 + kt;                                      \
      const int sw = (r & 7) << 4;                                            \
      const int co = hi * 16;                                                 \
      const char* bp = (CB) + r * 128;                                        \
      _Pragma("unroll") for (int ks = 0; ks < 4; ++ks) {                      \
        short8 bfr = *(const short8*)(bp + ((co + 32 * ks) ^ sw));            \
        acc0 = __builtin_amdgcn_mfma_f32_32x32x16_bf16(A[kt * 4 + ks], bfr,   \
                                                       acc0, 0, 0, 0);        \
      }                                                                       \
    }                                                                         \
    {                                                                         \
      const int r  = th * 64 + 32 + l31 + kt;                                 \
      const int sw = (r & 7) << 4;                                            \
      const int co = hi * 16;                                                 \
      const char* bp = (CB) + r * 128;                                        \
      _Pragma("unroll") for (int ks = 0; ks < 4; ++ks) {                      \
        short8 bfr = *(const short8*)(bp + ((co + 32 * ks) ^ sw));            \
        acc1 = __builtin_amdgcn_mfma_f32_32x32x16_bf16(A[kt * 4 + ks], bfr,   \
                                                       acc1, 0, 0, 0);        \
      }                                                                       \
    }                                                                         \
  }

  // ---- prologue: A0 first (oldest in vmcnt queue), then stages s0,s1,s2 ----
  short8 aP[12], aQ[12];
  LOAD_A(aP, 0)
  __builtin_amdgcn_sched_barrier(0);
  {
    const char* gb0 = slab_base(xT, n, idx[v * KK + 0], tb);
    const char* gb1 = slab_base(xT, n, idx[v * KK + 1], tb);
    const char* gb2 = slab_base(xT, n, idx[v * KK + 2], tb);
#pragma unroll
    for (int s = 0; s < KK; ++s) {
      const char* gb = (s == 0) ? gb0 : ((s == 1) ? gb1 : gb2);
#pragma unroll
      for (int q = 0; q < 4; ++q) {
        int c = wave + q * 4;                // c in 0..15
        int L = c * 1024 + lane * 16;
        int g = L ^ (((L >> 7) & 7) << 4);   // involution within 128B rows
        __builtin_amdgcn_global_load_lds(
            (const __attribute__((address_space(1))) void*)(gb + g),
            (__attribute__((address_space(3))) void*)(&xs[s][c * 1024]),
            16, 0, 0);
      }
      if (wave == 0) {                       // tail op: bytes 16384..17407
        int L = 16 * 1024 + lane * 16;       // (768B global over-read -> guard)
        int g = L ^ (((L >> 7) & 7) << 4);
        __builtin_amdgcn_global_load_lds(
            (const __attribute__((address_space(1))) void*)(gb + g),
            (__attribute__((address_space(3))) void*)(&xs[s][16 * 1024]),
            16, 0, 0);
      } else {                               // dummy: uniform 5 ops/slab/wave
        __builtin_amdgcn_global_load_lds(
            (const __attribute__((address_space(1))) void*)(gb + lane * 16),
            (__attribute__((address_space(3))) void*)(xs_dummy),
            16, 0, 0);
      }
      __builtin_amdgcn_sched_barrier(0);
    }
  }

  f32x16 acc0 = {}, acc1 = {};

  // ---- k = 0: wait own s0 (5 of 15 stage ops + A0 oldest) ----
  asm volatile("s_waitcnt vmcnt(10)" ::: "memory");
  __builtin_amdgcn_s_barrier();
  __builtin_amdgcn_sched_barrier(0);
  LOAD_A(aQ, 1)                              // prefetch A1 under k0 compute
  COMPUTE_K(xs[0], aP)

  // ---- k = 1: need s1; in-flight <= s2(5) + A1(12) ----
  asm volatile("s_waitcnt vmcnt(17)" ::: "memory");
  __builtin_amdgcn_s_barrier();
  __builtin_amdgcn_sched_barrier(0);
  COMPUTE_K(xs[1], aQ)

  // ---- k = 2: need s2; in-flight <= A1 leftovers (12) ----
  asm volatile("s_waitcnt vmcnt(12)" ::: "memory");
  __builtin_amdgcn_s_barrier();
  __builtin_amdgcn_sched_barrier(0);
  LOAD_A(aP, 2)                              // reuse aP (k0 MFMAs long done)
  COMPUTE_K(xs[2], aP)

#undef LOAD_A
#undef COMPUTE_K

  // epilogue: D col(t)=lane&31, row(o)=(reg&3)+8*(reg>>2)+4*(lane>>5)
  const float* bv = bias + v * COUTC;
#pragma unroll
  for (int s = 0; s < 2; ++s) {
    const f32x16& acc = s ? acc1 : acc0;
    const int t = tb + th * 64 + s * 32 + l31;
#pragma unroll
    for (int reg = 0; reg < 16; ++reg) {
      int o = os * 32 + 4 * hi + (reg & 3) + 8 * (reg >> 2);
      out[(((size_t)n * COUTC + o) * NV + v) * TLEN + t] = acc[reg] + bv[o];
    }
  }
}

// ================= FALLBACK PATH (round-1 fp32, known-good) =================
__global__ void prep_mask_kernel(const int* __restrict__ mask_raw,
                                 int* __restrict__ mask_out) {
  __shared__ int fmt;
  if (threadIdx.x == 0) {
    int ok = 1;
    for (int i = 0; i < 18; ++i) {
      int m = mask_raw[i];
      if (m != 0 && m != 1) ok = 0;
    }
    fmt = ok;
  }
  __syncthreads();
  int i = threadIdx.x;
  if (i < NV * KK) {
    int m;
    if (fmt) m = mask_raw[i];
    else     m = (((const unsigned char*)mask_raw)[i] != 0) ? 1 : 0;
    mask_out[i] = m;
  }
}

__global__ void prep_wt_kernel(const float* __restrict__ W,
                               float* __restrict__ Wt) {
  int v   = blockIdx.x / 9;
  int kkt = blockIdx.x % 9;
  const float* Wv = W + (size_t)v * COUTC * CINC * 9;
  float* dst = Wt + (size_t)blockIdx.x * (CINC * COUTC);
  for (int i = threadIdx.x; i < CINC * COUTC; i += 256) {
    int c = i >> 6;
    int o = i & 63;
    dst[i] = Wv[(o * CINC + c) * 9 + kkt];
  }
}

__global__ __launch_bounds__(256, 4) void lcn_main(
    const float* __restrict__ x, const float* __restrict__ Wt,
    const float* __restrict__ b, const int* __restrict__ idx,
    const int* __restrict__ maskn, float* __restrict__ out) {
  __shared__ float xsf[CINC][66];
  __shared__ float wsh[CINC][COUTC];
  const int tb  = blockIdx.x * 64;
  const int v   = blockIdx.y;
  const int n   = blockIdx.z;
  const int tid = threadIdx.x;
  const int t0  = tid & 63;
  const int og  = tid >> 6;
  float acc[16];
#pragma unroll
  for (int j = 0; j < 16; ++j) acc[j] = 0.f;
  for (int k = 0; k < KK; ++k) {
    const int vk = idx[v * KK + k];
    const int mk = maskn[v * KK + k];
    __syncthreads();
    for (int i = tid; i < CINC * 66; i += 256) {
      int c  = i / 66;
      int tt = i - c * 66;
      int gt = tb - 1 + tt;
      float val = 0.f;
      if (mk && gt >= 0 && gt < TLEN)
        val = x[(((size_t)n * CINC + c) * NV + vk) * TLEN + gt];
      xsf[c][tt] = val;
    }
    for (int kt = 0; kt < TKK; ++kt) {
      __syncthreads();
      const float4* src =
          (const float4*)(Wt + ((size_t)(v * KK + k) * TKK + kt) * (CINC * COUTC));
      for (int i = tid; i < CINC * COUTC / 4; i += 256)
        ((float4*)wsh)[i] = src[i];
      __syncthreads();
#pragma unroll 4
      for (int c = 0; c < CINC; ++c) {
        float xv = xsf[c][t0 + kt];
        const float4* wrow = (const float4*)&wsh[c][og * 16];
#pragma unroll
        for (int j4 = 0; j4 < 4; ++j4) {
          float4 wv = wrow[j4];
          acc[j4 * 4 + 0] = fmaf(wv.x, xv, acc[j4 * 4 + 0]);
          acc[j4 * 4 + 1] = fmaf(wv.y, xv, acc[j4 * 4 + 1]);
          acc[j4 * 4 + 2] = fmaf(wv.z, xv, acc[j4 * 4 + 2]);
          acc[j4 * 4 + 3] = fmaf(wv.w, xv, acc[j4 * 4 + 3]);
        }
      }
    }
  }
#pragma unroll
  for (int j = 0; j < 16; ++j) {
    int o = og * 16 + j;
    out[(((size_t)n * COUTC + o) * NV + v) * TLEN + tb + t0] =
        acc[j] + b[v * COUTC + o];
  }
}

extern "C" void kernel_launch(void* const* d_in, const int* in_sizes, int n_in,
                              void* d_out, int out_size, void* d_ws, size_t ws_size,
                              hipStream_t stream) {
  const float* x    = (const float*)d_in[0];
  const float* W    = (const float*)d_in[1];
  const float* b    = (const float*)d_in[2];
  const int*   idx  = (const int*)d_in[3];
  const void*  mask = (const void*)d_in[4];
  float* out = (float*)d_out;

  // ws: [0,512) maskn (fallback) | Wt3 1.84MB | xT padded 26.3MB | guard
  const size_t WT3_BYTES = (size_t)NV * 9 * 4096 * sizeof(__hip_bfloat16);
  const size_t XT_BYTES  = (size_t)NB * NV * XT_ROWS * CINC * sizeof(__hip_bfloat16);
  const size_t NEED      = 512 + WT3_BYTES + XT_BYTES + 2048;

  if (ws_size >= NEED) {
    __hip_bfloat16* Wt3 = (__hip_bfloat16*)((char*)d_ws + 512);
    __hip_bfloat16* xT  = (__hip_bfloat16*)((char*)d_ws + 512 + WT3_BYTES);
    hipLaunchKernelGGL(prep_all, dim3(NWT3BLK + 8 * NV * NB), dim3(256), 0,
                       stream, x, W, (const unsigned char*)mask, Wt3, xT);
    hipLaunchKernelGGL(lcn_mfma32, dim3(TLEN / 128, NB, NV), dim3(256), 0,
                       stream, xT, Wt3, b, idx, out);
  } else {
    int*   maskn = (int*)d_ws;
    float* Wt    = (float*)((char*)d_ws + 512);
    hipLaunchKernelGGL(prep_mask_kernel, dim3(1), dim3(128), 0, stream,
                       (const int*)mask, maskn);
    hipLaunchKernelGGL(prep_wt_kernel, dim3(NV * KK * TKK), dim3(256), 0, stream,
                       W, Wt);
    hipLaunchKernelGGL(lcn_main, dim3(TLEN / 64, NV, NB), dim3(256), 0, stream,
                       x, Wt, b, idx, maskn, out);
  }
}